// Round 4
// baseline (640.570 us; speedup 1.0000x reference)
//
#include <hip/hip_runtime.h>
#include <math.h>

// ---------------- workspace layout (bytes unless _F) ----------------
#define WS_M1_F    0           // 4096 f32
#define WS_M2_F    4096        // 4096 f32
#define WS_BNSC_F  8192        // 64 f32
#define WS_BNSH_F  8256        // 64 f32
#define WS_WT_F    8448        // 12288 f32 (conv_w transposed [ik][o])
#define OFF_W1T    83968       // u16[32*2048]  attn_w1^T fp16  -> +131072 = 215040
#define OFF_CW1H   215040      // u16[128*2048] cls_w1^T bf16-hi -> +524288 = 739328
#define OFF_CW1L   739328      // u16[128*2048] cls_w1^T bf16-lo -> +524288 = 1263616
#define OFF_XCUR   1263616     // f32[4096*960] conv+bn output -> +15728640 = 16992256
#define OFF_DYN    16992256    // per-chunk: pots fp16, scores f32, ctx hi/lo
#define PER_BATCH_POTS_B 61440 // 15*2048*2
#define PER_BATCH_SC_B   60    // 15*4
#define PER_BATCH_CTX_B  8192  // 2048*2 *2 planes

typedef _Float16 v8h __attribute__((ext_vector_type(8)));
typedef short v8s __attribute__((ext_vector_type(8)));
typedef float v4f __attribute__((ext_vector_type(4)));
typedef float v16f __attribute__((ext_vector_type(16)));

__device__ __forceinline__ unsigned short f2h_u(float x) {
  _Float16 h = (_Float16)x;
  union { _Float16 h; unsigned short u; } v; v.h = h; return v.u;
}
__device__ __forceinline__ unsigned short bf16t(float x) {
  union { float f; unsigned int u; } v; v.f = x; return (unsigned short)(v.u >> 16);
}
__device__ __forceinline__ float bf16tof(unsigned short s) {
  union { unsigned int u; float f; } v; v.u = ((unsigned int)s) << 16; return v.f;
}

// ================= K1: prep (multi-block) =================
__global__ __launch_bounds__(256) void k_prep(
    const float* __restrict__ mask1, const float* __restrict__ mask2,
    const float* __restrict__ conv_w, const float* __restrict__ conv_b,
    const float* __restrict__ bn_gamma, const float* __restrict__ bn_beta,
    const float* __restrict__ bn_mean, const float* __restrict__ bn_var,
    const float* __restrict__ attn_w1, const float* __restrict__ cls_w1,
    float* __restrict__ wsf, unsigned short* __restrict__ w1t,
    unsigned short* __restrict__ cw1h, unsigned short* __restrict__ cw1l)
{
  const int gid = blockIdx.x * 256 + threadIdx.x;
  const int gsz = gridDim.x * 256;
  float* m1 = wsf + WS_M1_F;
  float* m2 = wsf + WS_M2_F;
  float* bnsc = wsf + WS_BNSC_F;
  float* bnsh = wsf + WS_BNSH_F;
  float* wT = wsf + WS_WT_F;
  for (int e = gid; e < 4096; e += gsz) {
    int i = e >> 6, j = e & 63;
    float s1 = mask1[e] + mask1[j * 64 + i];
    float s2 = mask2[e] + mask2[j * 64 + i];
    m1[e] = 0.5f / (1.f + expf(-s1));
    m2[e] = 0.5f / (1.f + expf(-s2));
  }
  for (int e = gid; e < 64; e += gsz) {
    float sc = bn_gamma[e] * rsqrtf(bn_var[e] + 1e-5f);
    bnsc[e] = sc;
    bnsh[e] = (conv_b[e] - bn_mean[e]) * sc + bn_beta[e];
  }
  for (int e = gid; e < 12288; e += gsz) {
    int o = e / 192, ik = e % 192;
    wT[ik * 64 + o] = conv_w[e];
  }
  for (int e = gid; e < 65536; e += gsz) {
    int n = e >> 11, i = e & 2047;
    w1t[e] = f2h_u(attn_w1[i * 32 + n]);
  }
  for (int e = gid; e < 262144; e += gsz) {
    int n = e >> 11, k = e & 2047;
    float x = cls_w1[k * 128 + n];
    unsigned short h = bf16t(x);
    cw1h[e] = h;
    cw1l[e] = bf16t(x - bf16tof(h));
  }
}

// ================= K1b: conv+BN for all batches =================
__global__ __launch_bounds__(256) void k_conv(
    const float* __restrict__ X_seq, const float* __restrict__ wsf,
    float* __restrict__ xcur_g)
{
  __shared__ float xraw[960];
  const int tid = threadIdx.x;
  const int lane = tid & 63;
  const int wv = tid >> 6;
  const int b = blockIdx.x;
  const float* bnsc = wsf + WS_BNSC_F;
  const float* bnsh = wsf + WS_BNSH_F;
  const float* wT = wsf + WS_WT_F;
  for (int e = tid; e < 960; e += 256) xraw[e] = X_seq[(size_t)b * 960 + e];
  __syncthreads();
  const int o = lane;
  const int t0 = wv, t1 = wv + 4, t2 = wv + 8, t3 = wv + 12;
  float a0 = 0.f, a1 = 0.f, a2 = 0.f, a3 = 0.f;
  for (int i = 0; i < 64; ++i) {
    const float w0 = wT[(3 * i + 0) * 64 + o];
    const float w1 = wT[(3 * i + 1) * 64 + o];
    const float w2 = wT[(3 * i + 2) * 64 + o];
    float xa = (t0 >= 2) ? xraw[(t0 - 2) * 64 + i] : 0.f;
    float xb = (t0 >= 1) ? xraw[(t0 - 1) * 64 + i] : 0.f;
    a0 += w0 * xa + w1 * xb + w2 * xraw[t0 * 64 + i];
    a1 += w0 * xraw[(t1 - 2) * 64 + i] + w1 * xraw[(t1 - 1) * 64 + i] + w2 * xraw[t1 * 64 + i];
    a2 += w0 * xraw[(t2 - 2) * 64 + i] + w1 * xraw[(t2 - 1) * 64 + i] + w2 * xraw[t2 * 64 + i];
    if (t3 < 15)
      a3 += w0 * xraw[(t3 - 2) * 64 + i] + w1 * xraw[(t3 - 1) * 64 + i] + w2 * xraw[t3 * 64 + i];
  }
  const float sc = bnsc[o], sh = bnsh[o];
  float* xg = xcur_g + (size_t)b * 960;
  xg[t0 * 64 + o] = a0 * sc + sh;
  xg[t1 * 64 + o] = a1 * sc + sh;
  xg[t2 * 64 + o] = a2 * sc + sh;
  if (t3 < 15) xg[t3 * 64 + o] = a3 * sc + sh;
}

// ================= K2: recurrence, 3-barrier pipelined =================
__global__ __launch_bounds__(256) void k_main(
    const float* __restrict__ L_norm, const float* __restrict__ xcur_g,
    const float* __restrict__ gcn1_w, const float* __restrict__ gcn1_b,
    const float* __restrict__ gcn2_w, const float* __restrict__ gcn2_b,
    const float* __restrict__ beta2p,
    const float* __restrict__ wsf, unsigned short* __restrict__ pots,
    int b0)
{
  __shared__ float xcur[960];
  __shared__ float zp[2 * 64];
  __shared__ __align__(16) unsigned short spk1T[16 * 72];
  __shared__ __align__(16) float Z2f[64 * 20];

  const int tid = threadIdx.x;
  const int lane = tid & 63;
  const int wv = tid >> 6;
  const int b = b0 + blockIdx.x;

  const float* m1 = wsf + WS_M1_F;
  const float* m2 = wsf + WS_M2_F;

  for (int e = tid; e < 960; e += 256) xcur[e] = xcur_g[(size_t)b * 960 + e];

  // ---- L1 half in registers (waves 2,3): wave holds L1[lane][kb..kb+31] ----
  float L1h[32];
  const int kb1 = (wv & 1) * 32;
  if (wv >= 2) {
    const float* Lb = L_norm + (size_t)b * 4096 + lane * 64 + kb1;
    const float* mr = m1 + lane * 64 + kb1;
#pragma unroll
    for (int q4 = 0; q4 < 8; ++q4) {
      float4 lv = *(const float4*)(Lb + 4 * q4);
      float4 mv = *(const float4*)(mr + 4 * q4);
      L1h[4 * q4 + 0] = lv.x * mv.x;
      L1h[4 * q4 + 1] = lv.y * mv.y;
      L1h[4 * q4 + 2] = lv.z * mv.z;
      L1h[4 * q4 + 3] = lv.w * mv.w;
    }
  }

  // ---- Stage-A A-fragments: L2 rows [16wv,16wv+16), hi/lo bf16 split ----
  v8s A_hi[2], A_lo[2];
  {
    const int irow = wv * 16 + (lane & 15);
    const int quad = (lane >> 4) & 3;
#pragma unroll
    for (int kb = 0; kb < 2; ++kb) {
      const float* Lb = L_norm + (size_t)b * 4096 + irow * 64 + kb * 32 + quad * 8;
      const float* mr = m2 + irow * 64 + kb * 32 + quad * 8;
      float4 la = *(const float4*)Lb, lb2 = *(const float4*)(Lb + 4);
      float4 ma = *(const float4*)mr, mb = *(const float4*)(mr + 4);
      float v[8] = { la.x * ma.x, la.y * ma.y, la.z * ma.z, la.w * ma.w,
                     lb2.x * mb.x, lb2.y * mb.y, lb2.z * mb.z, lb2.w * mb.w };
#pragma unroll
      for (int e = 0; e < 8; ++e) {
        unsigned short h = bf16t(v[e]);
        unsigned short l = bf16t(v[e] - bf16tof(h));
        A_hi[kb][e] = (short)h;
        A_lo[kb][e] = (short)l;
      }
    }
  }

  // ---- Stage-B B-fragments: W2 hi/lo (waves 0,1 use) ----
  v8s W_hi, W_lo;
  {
    const int n = lane & 31;
    const int kh = (lane >> 5) & 1;
#pragma unroll
    for (int e = 0; e < 8; ++e) {
      float x = gcn2_w[(kh * 8 + e) * 32 + n];
      unsigned short h = bf16t(x);
      unsigned short l = bf16t(x - bf16tof(h));
      W_hi[e] = (short)h;
      W_lo[e] = (short)l;
    }
  }

  const float b2h = gcn2_b[lane & 31];
  const int np = tid >> 3;
  const int cp = tid & 7;
  float w1c[2], b1c[2];
#pragma unroll
  for (int d = 0; d < 2; ++d) { w1c[d] = gcn1_w[2 * cp + d]; b1c[d] = gcn1_b[2 * cp + d]; }
  const float beta2 = beta2p[0];

  float mem_t = 0.f;                     // waves 2,3 only
  float mg1[4] = {0.f, 0.f, 0.f, 0.f};
  v16f mg2;
#pragma unroll
  for (int r = 0; r < 16; ++r) mg2[r] = 0.f;

  unsigned short* pbase = pots + (size_t)blockIdx.x * 30720 + (lane & 31);

  // stage-B body (waves 0,1): consumes Z2f, updates mg2, stores pots[tm1]
  auto stage_b = [&](int tm1) {
    const int m = lane & 31;
    const int half = lane >> 5;
    const float* zr = Z2f + (wv * 32 + m) * 20 + half * 8;
    float4 za = *(const float4*)zr;
    float4 zb = *(const float4*)(zr + 4);
    float vv[8] = {za.x, za.y, za.z, za.w, zb.x, zb.y, zb.z, zb.w};
    v8s Ah, Al;
#pragma unroll
    for (int e = 0; e < 8; ++e) {
      unsigned short h = bf16t(vv[e]);
      unsigned short l = bf16t(vv[e] - bf16tof(h));
      Ah[e] = (short)h;
      Al[e] = (short)l;
    }
    v16f acc;
#pragma unroll
    for (int r = 0; r < 16; ++r) {
      float rs = (mg2[r] > 1.f) ? 1.f : 0.f;
      acc[r] = fmaf(beta2, mg2[r], b2h - rs);
    }
    acc = __builtin_amdgcn_mfma_f32_32x32x16_bf16(Ah, W_hi, acc, 0, 0, 0);
    acc = __builtin_amdgcn_mfma_f32_32x32x16_bf16(Al, W_hi, acc, 0, 0, 0);
    acc = __builtin_amdgcn_mfma_f32_32x32x16_bf16(Ah, W_lo, acc, 0, 0, 0);
    mg2 = acc;
    unsigned short* pb = pbase + (size_t)tm1 * 2048;
#pragma unroll
    for (int r = 0; r < 16; ++r) {
      int i = wv * 32 + (r & 3) + 8 * (r >> 2) + 4 * half;
      pb[i * 32] = f2h_u(acc[r]);
    }
  };

  __syncthreads();

  for (int t = 0; t < 15; ++t) {
    // ---- phase A: waves 2,3 -> input LIF + z1 half; waves 0,1 -> stage-B(t-1)
    if (wv >= 2) {
      float xc = xcur[t * 64 + lane];
      float rs = (mem_t > 1.f) ? 1.f : 0.f;
      mem_t = 0.9f * mem_t + xc - rs;
      float sp = (mem_t > 1.f) ? 1.f : 0.f;
      int spi = __float_as_int(sp);
      float zh = 0.f;
#pragma unroll
      for (int k = 0; k < 32; ++k) {
        float s = __int_as_float(__builtin_amdgcn_readlane(spi, kb1 + k));
        zh = fmaf(s, L1h[k], zh);
      }
      zp[(wv & 1) * 64 + lane] = zh;
    } else if (t > 0) {
      stage_b(t - 1);
    }
    __syncthreads();
    // ---- P2: layer-1 LIF, write spk1^T bf16 bits ----
    {
      float2 q0 = *(const float2*)&zp[2 * np];
      float2 q1 = *(const float2*)&zp[64 + 2 * np];
      float z0 = q0.x + q1.x;
      float z1v = q0.y + q1.y;
#pragma unroll
      for (int d = 0; d < 2; ++d) {
        float cur0 = fmaf(z0, w1c[d], b1c[d]);
        float rs0 = (mg1[d * 2 + 0] > 1.f) ? 1.f : 0.f;
        mg1[d * 2 + 0] = 0.85f * mg1[d * 2 + 0] + cur0 - rs0;
        unsigned int bits0 = (mg1[d * 2 + 0] > 1.f) ? 0x3F80u : 0u;
        float cur1 = fmaf(z1v, w1c[d], b1c[d]);
        float rs1 = (mg1[d * 2 + 1] > 1.f) ? 1.f : 0.f;
        mg1[d * 2 + 1] = 0.85f * mg1[d * 2 + 1] + cur1 - rs1;
        unsigned int bits1 = (mg1[d * 2 + 1] > 1.f) ? 0x3F80u : 0u;
        *(unsigned int*)&spk1T[(2 * cp + d) * 72 + 2 * np] = bits0 | (bits1 << 16);
      }
    }
    __syncthreads();
    // ---- stage A: Z2 = L2 @ spk1 (16x16x32 bf16, exact binary B) ----
    {
      const int c = lane & 15;
      const int quad = (lane >> 4) & 3;
      const unsigned short* bp = spk1T + c * 72 + quad * 8;
      v8s B0 = *(const v8s*)(bp);
      v8s B1 = *(const v8s*)(bp + 32);
      v4f acc = {0.f, 0.f, 0.f, 0.f};
      acc = __builtin_amdgcn_mfma_f32_16x16x32_bf16(A_hi[0], B0, acc, 0, 0, 0);
      acc = __builtin_amdgcn_mfma_f32_16x16x32_bf16(A_lo[0], B0, acc, 0, 0, 0);
      acc = __builtin_amdgcn_mfma_f32_16x16x32_bf16(A_hi[1], B1, acc, 0, 0, 0);
      acc = __builtin_amdgcn_mfma_f32_16x16x32_bf16(A_lo[1], B1, acc, 0, 0, 0);
      const int r0 = wv * 16 + quad * 4;
#pragma unroll
      for (int r = 0; r < 4; ++r) Z2f[(r0 + r) * 20 + c] = acc[r];
    }
    __syncthreads();
  }
  // drain: stage-B for t=14
  if (wv < 2) stage_b(14);
}

// ================= K3a: scores GEMM (f16 MFMA from global) =================
__global__ __launch_bounds__(256) void k_score(
    const unsigned short* __restrict__ pots,
    const unsigned short* __restrict__ w1t,
    const float* __restrict__ attn_b1, const float* __restrict__ attn_w2,
    const float* __restrict__ attn_b2,
    float* __restrict__ scores)
{
  const int tid = threadIdx.x;
  const int lane = tid & 63;
  const int wv = tid >> 6;
  const int r0 = (blockIdx.x * 4 + wv) * 16;
  const int m = lane & 15;
  const int quad = lane >> 4;
  const int koff = quad * 8;

  const unsigned short* Ap = pots + (size_t)(r0 + m) * 2048 + koff;
  const unsigned short* B0p = w1t + (size_t)m * 2048 + koff;
  const unsigned short* B1p = w1t + (size_t)(m + 16) * 2048 + koff;
  v4f a0 = {0.f, 0.f, 0.f, 0.f}, a1 = {0.f, 0.f, 0.f, 0.f};
#pragma unroll 4
  for (int c = 0; c < 64; ++c) {
    v8h A = *(const v8h*)(Ap + c * 32);
    v8h B0 = *(const v8h*)(B0p + c * 32);
    v8h B1 = *(const v8h*)(B1p + c * 32);
    a0 = __builtin_amdgcn_mfma_f32_16x16x32_f16(A, B0, a0, 0, 0, 0);
    a1 = __builtin_amdgcn_mfma_f32_16x16x32_f16(A, B1, a1, 0, 0, 0);
  }
  const float b1a = attn_b1[m], b1b = attn_b1[m + 16];
  const float w2a = attn_w2[m], w2b = attn_w2[m + 16];
  const float b2 = attn_b2[0];
  float sc[4];
#pragma unroll
  for (int r = 0; r < 4; ++r) {
    float v = tanhf(a0[r] + b1a) * w2a + tanhf(a1[r] + b1b) * w2b;
    v += __shfl_xor(v, 1, 64);
    v += __shfl_xor(v, 2, 64);
    v += __shfl_xor(v, 4, 64);
    v += __shfl_xor(v, 8, 64);
    sc[r] = v + b2;
  }
  if (m == 0) {
    *(float4*)&scores[r0 + quad * 4] = make_float4(sc[0], sc[1], sc[2], sc[3]);
  }
}

// ================= K3b: softmax + ctx (streaming) =================
__global__ __launch_bounds__(256) void k_ctx(
    const unsigned short* __restrict__ pots, const float* __restrict__ scores,
    unsigned short* __restrict__ ctxh, unsigned short* __restrict__ ctxl)
{
  const int tid = threadIdx.x;
  const int b = blockIdx.x;
  const float* sb = scores + (size_t)b * 15;
  float s[15];
#pragma unroll
  for (int t = 0; t < 15; ++t) s[t] = sb[t];
  float mx = s[0];
#pragma unroll
  for (int t = 1; t < 15; ++t) mx = fmaxf(mx, s[t]);
  float den = 0.f;
#pragma unroll
  for (int t = 0; t < 15; ++t) { s[t] = expf(s[t] - mx); den += s[t]; }
  const float inv = 1.f / den;

  float cv[8] = {0.f, 0.f, 0.f, 0.f, 0.f, 0.f, 0.f, 0.f};
  const unsigned short* pp = pots + (size_t)b * 30720 + tid * 8;
#pragma unroll
  for (int t = 0; t < 15; ++t) {
    v8h pv = *(const v8h*)(pp + (size_t)t * 2048);
    const float w = s[t] * inv;
#pragma unroll
    for (int j = 0; j < 8; ++j) cv[j] = fmaf(w, (float)pv[j], cv[j]);
  }
  unsigned short hv[8], lv[8];
#pragma unroll
  for (int j = 0; j < 8; ++j) {
    unsigned short h = bf16t(cv[j]);
    hv[j] = h;
    lv[j] = bf16t(cv[j] - bf16tof(h));
  }
  *(uint4*)(ctxh + (size_t)b * 2048 + tid * 8) = *(const uint4*)hv;
  *(uint4*)(ctxl + (size_t)b * 2048 + tid * 8) = *(const uint4*)lv;
}

// ================= K4: classifier, MFMA bf16 hi/lo =================
__global__ __launch_bounds__(256) void k_cls(
    const unsigned short* __restrict__ ctxh, const unsigned short* __restrict__ ctxl,
    const unsigned short* __restrict__ cw1h, const unsigned short* __restrict__ cw1l,
    const float* __restrict__ cls_b1,
    const float* __restrict__ ln_g, const float* __restrict__ ln_b,
    const float* __restrict__ cls_w2, const float* __restrict__ cls_b2,
    float* __restrict__ out, int b0)
{
  __shared__ float hbuf[16 * 132];
  const int tid = threadIdx.x;
  const int lane = tid & 63;
  const int wv = tid >> 6;
  const int m = lane & 15;
  const int quad = lane >> 4;
  const int koff = quad * 8;
  const int r0l = blockIdx.x * 16;

  v4f a0 = {0.f, 0.f, 0.f, 0.f}, a1 = {0.f, 0.f, 0.f, 0.f};
  {
    const unsigned short* Ah = ctxh + (size_t)(r0l + m) * 2048;
    const unsigned short* Al = ctxl + (size_t)(r0l + m) * 2048;
    const int n0 = wv * 32 + m;
    const unsigned short* B0h = cw1h + (size_t)n0 * 2048;
    const unsigned short* B0l = cw1l + (size_t)n0 * 2048;
    const unsigned short* B1h = cw1h + (size_t)(n0 + 16) * 2048;
    const unsigned short* B1l = cw1l + (size_t)(n0 + 16) * 2048;
#pragma unroll 4
    for (int kc = 0; kc < 64; ++kc) {
      const int kb = kc * 32 + koff;
      v8s vAh = *(const v8s*)(Ah + kb);
      v8s vAl = *(const v8s*)(Al + kb);
      v8s vB0h = *(const v8s*)(B0h + kb);
      v8s vB0l = *(const v8s*)(B0l + kb);
      v8s vB1h = *(const v8s*)(B1h + kb);
      v8s vB1l = *(const v8s*)(B1l + kb);
      a0 = __builtin_amdgcn_mfma_f32_16x16x32_bf16(vAh, vB0h, a0, 0, 0, 0);
      a0 = __builtin_amdgcn_mfma_f32_16x16x32_bf16(vAl, vB0h, a0, 0, 0, 0);
      a0 = __builtin_amdgcn_mfma_f32_16x16x32_bf16(vAh, vB0l, a0, 0, 0, 0);
      a1 = __builtin_amdgcn_mfma_f32_16x16x32_bf16(vAh, vB1h, a1, 0, 0, 0);
      a1 = __builtin_amdgcn_mfma_f32_16x16x32_bf16(vAl, vB1h, a1, 0, 0, 0);
      a1 = __builtin_amdgcn_mfma_f32_16x16x32_bf16(vAh, vB1l, a1, 0, 0, 0);
    }
  }
  {
    const int n0 = wv * 32 + m;
    const float bb0 = cls_b1[n0], bb1 = cls_b1[n0 + 16];
#pragma unroll
    for (int r = 0; r < 4; ++r) {
      const int row = quad * 4 + r;
      hbuf[row * 132 + n0] = a0[r] + bb0;
      hbuf[row * 132 + n0 + 16] = a1[r] + bb1;
    }
  }
  __syncthreads();
  const float g0c = ln_g[lane], g1c = ln_g[lane + 64];
  const float b0c = ln_b[lane], b1c = ln_b[lane + 64];
  const float4 w2a = *(const float4*)(cls_w2 + lane * 4);
  const float4 w2b = *(const float4*)(cls_w2 + (lane + 64) * 4);
#pragma unroll
  for (int rr = 0; rr < 4; ++rr) {
    const int r = wv * 4 + rr;
    const float x0 = hbuf[r * 132 + lane];
    const float x1 = hbuf[r * 132 + 64 + lane];
    float s = x0 + x1, sq = x0 * x0 + x1 * x1;
#pragma unroll
    for (int mm = 32; mm >= 1; mm >>= 1) {
      s += __shfl_xor(s, mm, 64);
      sq += __shfl_xor(sq, mm, 64);
    }
    const float mu = s * (1.f / 128.f);
    const float var = sq * (1.f / 128.f) - mu * mu;
    const float rstd = rsqrtf(var + 1e-5f);
    float h0 = (x0 - mu) * rstd * g0c + b0c;
    float h1 = (x1 - mu) * rstd * g1c + b1c;
    h0 = 0.5f * h0 * (1.f + erff(h0 * 0.7071067811865475f));
    h1 = 0.5f * h1 * (1.f + erff(h1 * 0.7071067811865475f));
    float o0 = h0 * w2a.x + h1 * w2b.x;
    float o1 = h0 * w2a.y + h1 * w2b.y;
    float o2 = h0 * w2a.z + h1 * w2b.z;
    float o3 = h0 * w2a.w + h1 * w2b.w;
#pragma unroll
    for (int mm = 32; mm >= 1; mm >>= 1) {
      o0 += __shfl_xor(o0, mm, 64);
      o1 += __shfl_xor(o1, mm, 64);
      o2 += __shfl_xor(o2, mm, 64);
      o3 += __shfl_xor(o3, mm, 64);
    }
    if (lane == 0) {
      *(float4*)(out + (size_t)(b0 + r0l + r) * 4) =
          make_float4(o0 + cls_b2[0], o1 + cls_b2[1], o2 + cls_b2[2], o3 + cls_b2[3]);
    }
  }
}

// ================= host =================
extern "C" void kernel_launch(void* const* d_in, const int* in_sizes, int n_in,
                              void* d_out, int out_size, void* d_ws, size_t ws_size,
                              hipStream_t stream) {
  const float* L_norm   = (const float*)d_in[0];
  const float* X_seq    = (const float*)d_in[1];
  const float* conv_w   = (const float*)d_in[2];
  const float* conv_b   = (const float*)d_in[3];
  const float* bn_gamma = (const float*)d_in[4];
  const float* bn_beta  = (const float*)d_in[5];
  const float* bn_mean  = (const float*)d_in[6];
  const float* bn_var   = (const float*)d_in[7];
  const float* gcn1_w   = (const float*)d_in[8];
  const float* gcn1_b   = (const float*)d_in[9];
  const float* mask1    = (const float*)d_in[10];
  const float* gcn2_w   = (const float*)d_in[11];
  const float* gcn2_b   = (const float*)d_in[12];
  const float* mask2    = (const float*)d_in[13];
  const float* beta2    = (const float*)d_in[14];
  const float* attn_w1  = (const float*)d_in[15];
  const float* attn_b1  = (const float*)d_in[16];
  const float* attn_w2  = (const float*)d_in[17];
  const float* attn_b2  = (const float*)d_in[18];
  const float* cls_w1   = (const float*)d_in[19];
  const float* cls_b1   = (const float*)d_in[20];
  const float* ln_gamma = (const float*)d_in[21];
  const float* ln_beta  = (const float*)d_in[22];
  const float* cls_w2   = (const float*)d_in[23];
  const float* cls_b2   = (const float*)d_in[24];

  char* ws = (char*)d_ws;
  float* wsf = (float*)d_ws;
  unsigned short* w1t  = (unsigned short*)(ws + OFF_W1T);
  unsigned short* cw1h = (unsigned short*)(ws + OFF_CW1H);
  unsigned short* cw1l = (unsigned short*)(ws + OFF_CW1L);
  float* xcur_g = (float*)(ws + OFF_XCUR);

  long long avail = (long long)ws_size - (long long)OFF_DYN;
  long long per = PER_BATCH_POTS_B + PER_BATCH_SC_B + PER_BATCH_CTX_B;
  int chunk = 4096;
  if (avail < per * 4096LL) {
    long long c = (avail > 0) ? (avail / per) : 64;
    if (c > 4096) c = 4096;
    c &= ~63LL;
    if (c < 64) c = 64;
    chunk = (int)c;
  }
  unsigned short* pots = (unsigned short*)(ws + OFF_DYN);
  float* scores = (float*)(ws + OFF_DYN + (size_t)chunk * PER_BATCH_POTS_B);
  unsigned short* ctxh = (unsigned short*)((char*)scores + (size_t)chunk * PER_BATCH_SC_B);
  unsigned short* ctxl = ctxh + (size_t)chunk * 2048;

  hipLaunchKernelGGL(k_prep, dim3(64), dim3(256), 0, stream,
                     mask1, mask2, conv_w, conv_b, bn_gamma, bn_beta, bn_mean, bn_var,
                     attn_w1, cls_w1, wsf, w1t, cw1h, cw1l);
  hipLaunchKernelGGL(k_conv, dim3(4096), dim3(256), 0, stream,
                     X_seq, wsf, xcur_g);

  for (int b0 = 0; b0 < 4096; b0 += chunk) {
    int cur = 4096 - b0;
    if (cur > chunk) cur = chunk;
    hipLaunchKernelGGL(k_main, dim3(cur), dim3(256), 0, stream,
                       L_norm, xcur_g, gcn1_w, gcn1_b, gcn2_w, gcn2_b, beta2,
                       wsf, pots, b0);
    hipLaunchKernelGGL(k_score, dim3(cur * 15 / 64), dim3(256), 0, stream,
                       pots, w1t, attn_b1, attn_w2, attn_b2, scores);
    hipLaunchKernelGGL(k_ctx, dim3(cur), dim3(256), 0, stream,
                       pots, scores, ctxh, ctxl);
    hipLaunchKernelGGL(k_cls, dim3(cur / 16), dim3(256), 0, stream,
                       ctxh, ctxl, cw1h, cw1l, cls_b1, ln_gamma, ln_beta, cls_w2, cls_b2,
                       (float*)d_out, b0);
  }
}

// Round 5
// 604.944 us; speedup vs baseline: 1.0589x; 1.0589x over previous
//
#include <hip/hip_runtime.h>
#include <math.h>

// ---------------- workspace layout (bytes unless _F) ----------------
#define WS_M1_F    0           // 4096 f32
#define WS_M2_F    4096        // 4096 f32
#define WS_BNSC_F  8192        // 64 f32
#define WS_BNSH_F  8256        // 64 f32
#define WS_WT_F    8448        // 12288 f32 (conv_w transposed [ik][o])
#define OFF_W1T    83968       // u16[32*2048]  attn_w1^T fp16  -> +131072 = 215040
#define OFF_CW1H   215040      // u16[128*2048] cls_w1^T bf16-hi -> +524288 = 739328
#define OFF_CW1L   739328      // u16[128*2048] cls_w1^T bf16-lo -> +524288 = 1263616
#define OFF_XCUR   1263616     // f32[4096*960] conv+bn output -> +15728640 = 16992256
#define OFF_DYN    16992256    // per-chunk: pots fp16 (+4KB slack), ctx hi/lo
#define PER_BATCH_POTS_B 61440 // 15*2048*2
#define PER_BATCH_CTX_B  8192  // 2048*2 *2 planes

typedef _Float16 v8h __attribute__((ext_vector_type(8)));
typedef short v8s __attribute__((ext_vector_type(8)));
typedef float v4f __attribute__((ext_vector_type(4)));
typedef float v16f __attribute__((ext_vector_type(16)));

__device__ __forceinline__ unsigned short f2h_u(float x) {
  _Float16 h = (_Float16)x;
  union { _Float16 h; unsigned short u; } v; v.h = h; return v.u;
}
__device__ __forceinline__ unsigned short bf16t(float x) {
  union { float f; unsigned int u; } v; v.f = x; return (unsigned short)(v.u >> 16);
}
__device__ __forceinline__ float bf16tof(unsigned short s) {
  union { unsigned int u; float f; } v; v.u = ((unsigned int)s) << 16; return v.f;
}

// ================= K1: prep (multi-block) =================
__global__ __launch_bounds__(256) void k_prep(
    const float* __restrict__ mask1, const float* __restrict__ mask2,
    const float* __restrict__ conv_w, const float* __restrict__ conv_b,
    const float* __restrict__ bn_gamma, const float* __restrict__ bn_beta,
    const float* __restrict__ bn_mean, const float* __restrict__ bn_var,
    const float* __restrict__ attn_w1, const float* __restrict__ cls_w1,
    float* __restrict__ wsf, unsigned short* __restrict__ w1t,
    unsigned short* __restrict__ cw1h, unsigned short* __restrict__ cw1l)
{
  const int gid = blockIdx.x * 256 + threadIdx.x;
  const int gsz = gridDim.x * 256;
  float* m1 = wsf + WS_M1_F;
  float* m2 = wsf + WS_M2_F;
  float* bnsc = wsf + WS_BNSC_F;
  float* bnsh = wsf + WS_BNSH_F;
  float* wT = wsf + WS_WT_F;
  for (int e = gid; e < 4096; e += gsz) {
    int i = e >> 6, j = e & 63;
    float s1 = mask1[e] + mask1[j * 64 + i];
    float s2 = mask2[e] + mask2[j * 64 + i];
    m1[e] = 0.5f / (1.f + expf(-s1));
    m2[e] = 0.5f / (1.f + expf(-s2));
  }
  for (int e = gid; e < 64; e += gsz) {
    float sc = bn_gamma[e] * rsqrtf(bn_var[e] + 1e-5f);
    bnsc[e] = sc;
    bnsh[e] = (conv_b[e] - bn_mean[e]) * sc + bn_beta[e];
  }
  for (int e = gid; e < 12288; e += gsz) {
    int o = e / 192, ik = e % 192;
    wT[ik * 64 + o] = conv_w[e];
  }
  for (int e = gid; e < 65536; e += gsz) {
    int n = e >> 11, i = e & 2047;
    w1t[e] = f2h_u(attn_w1[i * 32 + n]);
  }
  for (int e = gid; e < 262144; e += gsz) {
    int n = e >> 11, k = e & 2047;
    float x = cls_w1[k * 128 + n];
    unsigned short h = bf16t(x);
    cw1h[e] = h;
    cw1l[e] = bf16t(x - bf16tof(h));
  }
}

// ================= K1b: conv+BN for all batches =================
__global__ __launch_bounds__(256) void k_conv(
    const float* __restrict__ X_seq, const float* __restrict__ wsf,
    float* __restrict__ xcur_g)
{
  __shared__ float xraw[960];
  const int tid = threadIdx.x;
  const int lane = tid & 63;
  const int wv = tid >> 6;
  const int b = blockIdx.x;
  const float* bnsc = wsf + WS_BNSC_F;
  const float* bnsh = wsf + WS_BNSH_F;
  const float* wT = wsf + WS_WT_F;
  for (int e = tid; e < 960; e += 256) xraw[e] = X_seq[(size_t)b * 960 + e];
  __syncthreads();
  const int o = lane;
  const int t0 = wv, t1 = wv + 4, t2 = wv + 8, t3 = wv + 12;
  float a0 = 0.f, a1 = 0.f, a2 = 0.f, a3 = 0.f;
  for (int i = 0; i < 64; ++i) {
    const float w0 = wT[(3 * i + 0) * 64 + o];
    const float w1 = wT[(3 * i + 1) * 64 + o];
    const float w2 = wT[(3 * i + 2) * 64 + o];
    float xa = (t0 >= 2) ? xraw[(t0 - 2) * 64 + i] : 0.f;
    float xb = (t0 >= 1) ? xraw[(t0 - 1) * 64 + i] : 0.f;
    a0 += w0 * xa + w1 * xb + w2 * xraw[t0 * 64 + i];
    a1 += w0 * xraw[(t1 - 2) * 64 + i] + w1 * xraw[(t1 - 1) * 64 + i] + w2 * xraw[t1 * 64 + i];
    a2 += w0 * xraw[(t2 - 2) * 64 + i] + w1 * xraw[(t2 - 1) * 64 + i] + w2 * xraw[t2 * 64 + i];
    if (t3 < 15)
      a3 += w0 * xraw[(t3 - 2) * 64 + i] + w1 * xraw[(t3 - 1) * 64 + i] + w2 * xraw[t3 * 64 + i];
  }
  const float sc = bnsc[o], sh = bnsh[o];
  float* xg = xcur_g + (size_t)b * 960;
  xg[t0 * 64 + o] = a0 * sc + sh;
  xg[t1 * 64 + o] = a1 * sc + sh;
  xg[t2 * 64 + o] = a2 * sc + sh;
  if (t3 < 15) xg[t3 * 64 + o] = a3 * sc + sh;
}

// ================= K2: recurrence, 3-barrier pipelined =================
__global__ __launch_bounds__(256) void k_main(
    const float* __restrict__ L_norm, const float* __restrict__ xcur_g,
    const float* __restrict__ gcn1_w, const float* __restrict__ gcn1_b,
    const float* __restrict__ gcn2_w, const float* __restrict__ gcn2_b,
    const float* __restrict__ beta2p,
    const float* __restrict__ wsf, unsigned short* __restrict__ pots,
    int b0)
{
  __shared__ float xcur[960];
  __shared__ float zp[2 * 64];
  __shared__ __align__(16) unsigned short spk1T[16 * 72];
  __shared__ __align__(16) float Z2f[64 * 20];

  const int tid = threadIdx.x;
  const int lane = tid & 63;
  const int wv = tid >> 6;
  const int b = b0 + blockIdx.x;

  const float* m1 = wsf + WS_M1_F;
  const float* m2 = wsf + WS_M2_F;

  for (int e = tid; e < 960; e += 256) xcur[e] = xcur_g[(size_t)b * 960 + e];

  float L1h[32];
  const int kb1 = (wv & 1) * 32;
  if (wv >= 2) {
    const float* Lb = L_norm + (size_t)b * 4096 + lane * 64 + kb1;
    const float* mr = m1 + lane * 64 + kb1;
#pragma unroll
    for (int q4 = 0; q4 < 8; ++q4) {
      float4 lv = *(const float4*)(Lb + 4 * q4);
      float4 mv = *(const float4*)(mr + 4 * q4);
      L1h[4 * q4 + 0] = lv.x * mv.x;
      L1h[4 * q4 + 1] = lv.y * mv.y;
      L1h[4 * q4 + 2] = lv.z * mv.z;
      L1h[4 * q4 + 3] = lv.w * mv.w;
    }
  }

  v8s A_hi[2], A_lo[2];
  {
    const int irow = wv * 16 + (lane & 15);
    const int quad = (lane >> 4) & 3;
#pragma unroll
    for (int kb = 0; kb < 2; ++kb) {
      const float* Lb = L_norm + (size_t)b * 4096 + irow * 64 + kb * 32 + quad * 8;
      const float* mr = m2 + irow * 64 + kb * 32 + quad * 8;
      float4 la = *(const float4*)Lb, lb2 = *(const float4*)(Lb + 4);
      float4 ma = *(const float4*)mr, mb = *(const float4*)(mr + 4);
      float v[8] = { la.x * ma.x, la.y * ma.y, la.z * ma.z, la.w * ma.w,
                     lb2.x * mb.x, lb2.y * mb.y, lb2.z * mb.z, lb2.w * mb.w };
#pragma unroll
      for (int e = 0; e < 8; ++e) {
        unsigned short h = bf16t(v[e]);
        unsigned short l = bf16t(v[e] - bf16tof(h));
        A_hi[kb][e] = (short)h;
        A_lo[kb][e] = (short)l;
      }
    }
  }

  v8s W_hi, W_lo;
  {
    const int n = lane & 31;
    const int kh = (lane >> 5) & 1;
#pragma unroll
    for (int e = 0; e < 8; ++e) {
      float x = gcn2_w[(kh * 8 + e) * 32 + n];
      unsigned short h = bf16t(x);
      unsigned short l = bf16t(x - bf16tof(h));
      W_hi[e] = (short)h;
      W_lo[e] = (short)l;
    }
  }

  const float b2h = gcn2_b[lane & 31];
  const int np = tid >> 3;
  const int cp = tid & 7;
  float w1c[2], b1c[2];
#pragma unroll
  for (int d = 0; d < 2; ++d) { w1c[d] = gcn1_w[2 * cp + d]; b1c[d] = gcn1_b[2 * cp + d]; }
  const float beta2 = beta2p[0];

  float mem_t = 0.f;
  float mg1[4] = {0.f, 0.f, 0.f, 0.f};
  v16f mg2;
#pragma unroll
  for (int r = 0; r < 16; ++r) mg2[r] = 0.f;

  unsigned short* pbase = pots + (size_t)blockIdx.x * 30720 + (lane & 31);

  auto stage_b = [&](int tm1) {
    const int m = lane & 31;
    const int half = lane >> 5;
    const float* zr = Z2f + (wv * 32 + m) * 20 + half * 8;
    float4 za = *(const float4*)zr;
    float4 zb = *(const float4*)(zr + 4);
    float vv[8] = {za.x, za.y, za.z, za.w, zb.x, zb.y, zb.z, zb.w};
    v8s Ah, Al;
#pragma unroll
    for (int e = 0; e < 8; ++e) {
      unsigned short h = bf16t(vv[e]);
      unsigned short l = bf16t(vv[e] - bf16tof(h));
      Ah[e] = (short)h;
      Al[e] = (short)l;
    }
    v16f acc;
#pragma unroll
    for (int r = 0; r < 16; ++r) {
      float rs = (mg2[r] > 1.f) ? 1.f : 0.f;
      acc[r] = fmaf(beta2, mg2[r], b2h - rs);
    }
    acc = __builtin_amdgcn_mfma_f32_32x32x16_bf16(Ah, W_hi, acc, 0, 0, 0);
    acc = __builtin_amdgcn_mfma_f32_32x32x16_bf16(Al, W_hi, acc, 0, 0, 0);
    acc = __builtin_amdgcn_mfma_f32_32x32x16_bf16(Ah, W_lo, acc, 0, 0, 0);
    mg2 = acc;
    unsigned short* pb = pbase + (size_t)tm1 * 2048;
#pragma unroll
    for (int r = 0; r < 16; ++r) {
      int i = wv * 32 + (r & 3) + 8 * (r >> 2) + 4 * half;
      pb[i * 32] = f2h_u(acc[r]);
    }
  };

  __syncthreads();

  for (int t = 0; t < 15; ++t) {
    if (wv >= 2) {
      float xc = xcur[t * 64 + lane];
      float rs = (mem_t > 1.f) ? 1.f : 0.f;
      mem_t = 0.9f * mem_t + xc - rs;
      float sp = (mem_t > 1.f) ? 1.f : 0.f;
      int spi = __float_as_int(sp);
      float zh = 0.f;
#pragma unroll
      for (int k = 0; k < 32; ++k) {
        float s = __int_as_float(__builtin_amdgcn_readlane(spi, kb1 + k));
        zh = fmaf(s, L1h[k], zh);
      }
      zp[(wv & 1) * 64 + lane] = zh;
    } else if (t > 0) {
      stage_b(t - 1);
    }
    __syncthreads();
    {
      float2 q0 = *(const float2*)&zp[2 * np];
      float2 q1 = *(const float2*)&zp[64 + 2 * np];
      float z0 = q0.x + q1.x;
      float z1v = q0.y + q1.y;
#pragma unroll
      for (int d = 0; d < 2; ++d) {
        float cur0 = fmaf(z0, w1c[d], b1c[d]);
        float rs0 = (mg1[d * 2 + 0] > 1.f) ? 1.f : 0.f;
        mg1[d * 2 + 0] = 0.85f * mg1[d * 2 + 0] + cur0 - rs0;
        unsigned int bits0 = (mg1[d * 2 + 0] > 1.f) ? 0x3F80u : 0u;
        float cur1 = fmaf(z1v, w1c[d], b1c[d]);
        float rs1 = (mg1[d * 2 + 1] > 1.f) ? 1.f : 0.f;
        mg1[d * 2 + 1] = 0.85f * mg1[d * 2 + 1] + cur1 - rs1;
        unsigned int bits1 = (mg1[d * 2 + 1] > 1.f) ? 0x3F80u : 0u;
        *(unsigned int*)&spk1T[(2 * cp + d) * 72 + 2 * np] = bits0 | (bits1 << 16);
      }
    }
    __syncthreads();
    {
      const int c = lane & 15;
      const int quad = (lane >> 4) & 3;
      const unsigned short* bp = spk1T + c * 72 + quad * 8;
      v8s B0 = *(const v8s*)(bp);
      v8s B1 = *(const v8s*)(bp + 32);
      v4f acc = {0.f, 0.f, 0.f, 0.f};
      acc = __builtin_amdgcn_mfma_f32_16x16x32_bf16(A_hi[0], B0, acc, 0, 0, 0);
      acc = __builtin_amdgcn_mfma_f32_16x16x32_bf16(A_lo[0], B0, acc, 0, 0, 0);
      acc = __builtin_amdgcn_mfma_f32_16x16x32_bf16(A_hi[1], B1, acc, 0, 0, 0);
      acc = __builtin_amdgcn_mfma_f32_16x16x32_bf16(A_lo[1], B1, acc, 0, 0, 0);
      const int r0 = wv * 16 + quad * 4;
#pragma unroll
      for (int r = 0; r < 4; ++r) Z2f[(r0 + r) * 20 + c] = acc[r];
    }
    __syncthreads();
  }
  if (wv < 2) stage_b(14);
}

// ======== K3: fused attention (scores + softmax + ctx), one block/batch, no LDS staging ========
__global__ __launch_bounds__(256) void k_att(
    const unsigned short* __restrict__ pots,
    const unsigned short* __restrict__ w1t,
    const float* __restrict__ attn_b1, const float* __restrict__ attn_w2,
    const float* __restrict__ attn_b2,
    unsigned short* __restrict__ ctxh, unsigned short* __restrict__ ctxl)
{
  __shared__ float sred[8 * 256];
  __shared__ __align__(16) float wbuf[4 * 16];
  const int tid = threadIdx.x;
  const int lane = tid & 63;
  const int wv = tid >> 6;
  const int m = lane & 15;
  const int quad = lane >> 4;
  const int koff = quad * 8;
  const unsigned short* pb = pots + (size_t)blockIdx.x * 30720;

  // ---- phase 1: projection s[t][n] via f16 MFMA; wave wv covers k-quarter ----
  v4f a0 = {0.f, 0.f, 0.f, 0.f}, a1 = {0.f, 0.f, 0.f, 0.f};
  {
    const unsigned short* Ap = pb + (size_t)m * 2048 + koff;    // A row m = t (row 15 garbage, discarded)
    const unsigned short* B0p = w1t + (size_t)m * 2048 + koff;
    const unsigned short* B1p = w1t + (size_t)(m + 16) * 2048 + koff;
#pragma unroll 4
    for (int c = wv * 16; c < wv * 16 + 16; ++c) {
      v8h A = *(const v8h*)(Ap + c * 32);
      v8h B0 = *(const v8h*)(B0p + c * 32);
      v8h B1 = *(const v8h*)(B1p + c * 32);
      a0 = __builtin_amdgcn_mfma_f32_16x16x32_f16(A, B0, a0, 0, 0, 0);
      a1 = __builtin_amdgcn_mfma_f32_16x16x32_f16(A, B1, a1, 0, 0, 0);
    }
  }
#pragma unroll
  for (int j = 0; j < 4; ++j) {
    sred[j * 256 + tid] = a0[j];
    sred[(j + 4) * 256 + tid] = a1[j];
  }
  __syncthreads();
  float s0[4], s1[4];
#pragma unroll
  for (int j = 0; j < 4; ++j) {
    s0[j] = sred[j * 256 + 0 * 64 + lane] + sred[j * 256 + 1 * 64 + lane]
          + sred[j * 256 + 2 * 64 + lane] + sred[j * 256 + 3 * 64 + lane];
    s1[j] = sred[(j + 4) * 256 + 0 * 64 + lane] + sred[(j + 4) * 256 + 1 * 64 + lane]
          + sred[(j + 4) * 256 + 2 * 64 + lane] + sred[(j + 4) * 256 + 3 * 64 + lane];
  }
  // ---- tanh, n-reduction within quad, softmax over t ----
  float wlar[16];
  {
    const int n = m;
    const float b1a = attn_b1[n], b1b = attn_b1[n + 16];
    const float w2a = attn_w2[n], w2b = attn_w2[n + 16];
    const float b2 = attn_b2[0];
    float sc[4];
#pragma unroll
    for (int r = 0; r < 4; ++r) {
      float v = tanhf(s0[r] + b1a) * w2a + tanhf(s1[r] + b1b) * w2b;
      v += __shfl_xor(v, 1, 64);
      v += __shfl_xor(v, 2, 64);
      v += __shfl_xor(v, 4, 64);
      v += __shfl_xor(v, 8, 64);
      sc[r] = v + b2;
    }
    float mx = -1e30f;
#pragma unroll
    for (int r = 0; r < 4; ++r) if (quad * 4 + r < 15) mx = fmaxf(mx, sc[r]);
    mx = fmaxf(mx, __shfl_xor(mx, 16, 64));
    mx = fmaxf(mx, __shfl_xor(mx, 32, 64));
    float e[4], den = 0.f;
#pragma unroll
    for (int r = 0; r < 4; ++r) {
      e[r] = (quad * 4 + r < 15) ? expf(sc[r] - mx) : 0.f;
      den += e[r];
    }
    den += __shfl_xor(den, 16, 64);
    den += __shfl_xor(den, 32, 64);
    const float inv = 1.f / den;
    if ((lane & 15) == 0) {
      v4f wq = {e[0] * inv, e[1] * inv, e[2] * inv, e[3] * inv};
      *(v4f*)&wbuf[wv * 16 + quad * 4] = wq;
    }
    // same-wave LDS RAW: ordered by lgkmcnt, no barrier needed
#pragma unroll
    for (int q4 = 0; q4 < 4; ++q4) {
      float4 v = *(const float4*)&wbuf[wv * 16 + q4 * 4];
      wlar[q4 * 4 + 0] = v.x; wlar[q4 * 4 + 1] = v.y;
      wlar[q4 * 4 + 2] = v.z; wlar[q4 * 4 + 3] = v.w;
    }
  }
  // ---- phase 2: ctx = sum_t w_t * pots[t] (global re-read, L2-hot) ----
  float cv[8] = {0.f, 0.f, 0.f, 0.f, 0.f, 0.f, 0.f, 0.f};
  const unsigned short* pp = pb + tid * 8;
#pragma unroll
  for (int t = 0; t < 15; ++t) {
    v8h pv = *(const v8h*)(pp + (size_t)t * 2048);
    const float w = wlar[t];
#pragma unroll
    for (int j = 0; j < 8; ++j) cv[j] = fmaf(w, (float)pv[j], cv[j]);
  }
  unsigned short hv[8], lv[8];
#pragma unroll
  for (int j = 0; j < 8; ++j) {
    unsigned short h = bf16t(cv[j]);
    hv[j] = h;
    lv[j] = bf16t(cv[j] - bf16tof(h));
  }
  *(uint4*)(ctxh + (size_t)blockIdx.x * 2048 + tid * 8) = *(const uint4*)hv;
  *(uint4*)(ctxl + (size_t)blockIdx.x * 2048 + tid * 8) = *(const uint4*)lv;
}

// ================= K4: classifier, MFMA bf16 hi/lo =================
__global__ __launch_bounds__(256) void k_cls(
    const unsigned short* __restrict__ ctxh, const unsigned short* __restrict__ ctxl,
    const unsigned short* __restrict__ cw1h, const unsigned short* __restrict__ cw1l,
    const float* __restrict__ cls_b1,
    const float* __restrict__ ln_g, const float* __restrict__ ln_b,
    const float* __restrict__ cls_w2, const float* __restrict__ cls_b2,
    float* __restrict__ out, int b0)
{
  __shared__ float hbuf[16 * 132];
  const int tid = threadIdx.x;
  const int lane = tid & 63;
  const int wv = tid >> 6;
  const int m = lane & 15;
  const int quad = lane >> 4;
  const int koff = quad * 8;
  const int r0l = blockIdx.x * 16;

  v4f a0 = {0.f, 0.f, 0.f, 0.f}, a1 = {0.f, 0.f, 0.f, 0.f};
  {
    const unsigned short* Ah = ctxh + (size_t)(r0l + m) * 2048;
    const unsigned short* Al = ctxl + (size_t)(r0l + m) * 2048;
    const int n0 = wv * 32 + m;
    const unsigned short* B0h = cw1h + (size_t)n0 * 2048;
    const unsigned short* B0l = cw1l + (size_t)n0 * 2048;
    const unsigned short* B1h = cw1h + (size_t)(n0 + 16) * 2048;
    const unsigned short* B1l = cw1l + (size_t)(n0 + 16) * 2048;
#pragma unroll 4
    for (int kc = 0; kc < 64; ++kc) {
      const int kb = kc * 32 + koff;
      v8s vAh = *(const v8s*)(Ah + kb);
      v8s vAl = *(const v8s*)(Al + kb);
      v8s vB0h = *(const v8s*)(B0h + kb);
      v8s vB0l = *(const v8s*)(B0l + kb);
      v8s vB1h = *(const v8s*)(B1h + kb);
      v8s vB1l = *(const v8s*)(B1l + kb);
      a0 = __builtin_amdgcn_mfma_f32_16x16x32_bf16(vAh, vB0h, a0, 0, 0, 0);
      a0 = __builtin_amdgcn_mfma_f32_16x16x32_bf16(vAl, vB0h, a0, 0, 0, 0);
      a0 = __builtin_amdgcn_mfma_f32_16x16x32_bf16(vAh, vB0l, a0, 0, 0, 0);
      a1 = __builtin_amdgcn_mfma_f32_16x16x32_bf16(vAh, vB1h, a1, 0, 0, 0);
      a1 = __builtin_amdgcn_mfma_f32_16x16x32_bf16(vAl, vB1h, a1, 0, 0, 0);
      a1 = __builtin_amdgcn_mfma_f32_16x16x32_bf16(vAh, vB1l, a1, 0, 0, 0);
    }
  }
  {
    const int n0 = wv * 32 + m;
    const float bb0 = cls_b1[n0], bb1 = cls_b1[n0 + 16];
#pragma unroll
    for (int r = 0; r < 4; ++r) {
      const int row = quad * 4 + r;
      hbuf[row * 132 + n0] = a0[r] + bb0;
      hbuf[row * 132 + n0 + 16] = a1[r] + bb1;
    }
  }
  __syncthreads();
  const float g0c = ln_g[lane], g1c = ln_g[lane + 64];
  const float b0c = ln_b[lane], b1c = ln_b[lane + 64];
  const float4 w2a = *(const float4*)(cls_w2 + lane * 4);
  const float4 w2b = *(const float4*)(cls_w2 + (lane + 64) * 4);
#pragma unroll
  for (int rr = 0; rr < 4; ++rr) {
    const int r = wv * 4 + rr;
    const float x0 = hbuf[r * 132 + lane];
    const float x1 = hbuf[r * 132 + 64 + lane];
    float s = x0 + x1, sq = x0 * x0 + x1 * x1;
#pragma unroll
    for (int mm = 32; mm >= 1; mm >>= 1) {
      s += __shfl_xor(s, mm, 64);
      sq += __shfl_xor(sq, mm, 64);
    }
    const float mu = s * (1.f / 128.f);
    const float var = sq * (1.f / 128.f) - mu * mu;
    const float rstd = rsqrtf(var + 1e-5f);
    float h0 = (x0 - mu) * rstd * g0c + b0c;
    float h1 = (x1 - mu) * rstd * g1c + b1c;
    h0 = 0.5f * h0 * (1.f + erff(h0 * 0.7071067811865475f));
    h1 = 0.5f * h1 * (1.f + erff(h1 * 0.7071067811865475f));
    float o0 = h0 * w2a.x + h1 * w2b.x;
    float o1 = h0 * w2a.y + h1 * w2b.y;
    float o2 = h0 * w2a.z + h1 * w2b.z;
    float o3 = h0 * w2a.w + h1 * w2b.w;
#pragma unroll
    for (int mm = 32; mm >= 1; mm >>= 1) {
      o0 += __shfl_xor(o0, mm, 64);
      o1 += __shfl_xor(o1, mm, 64);
      o2 += __shfl_xor(o2, mm, 64);
      o3 += __shfl_xor(o3, mm, 64);
    }
    if (lane == 0) {
      *(float4*)(out + (size_t)(b0 + r0l + r) * 4) =
          make_float4(o0 + cls_b2[0], o1 + cls_b2[1], o2 + cls_b2[2], o3 + cls_b2[3]);
    }
  }
}

// ================= host =================
extern "C" void kernel_launch(void* const* d_in, const int* in_sizes, int n_in,
                              void* d_out, int out_size, void* d_ws, size_t ws_size,
                              hipStream_t stream) {
  const float* L_norm   = (const float*)d_in[0];
  const float* X_seq    = (const float*)d_in[1];
  const float* conv_w   = (const float*)d_in[2];
  const float* conv_b   = (const float*)d_in[3];
  const float* bn_gamma = (const float*)d_in[4];
  const float* bn_beta  = (const float*)d_in[5];
  const float* bn_mean  = (const float*)d_in[6];
  const float* bn_var   = (const float*)d_in[7];
  const float* gcn1_w   = (const float*)d_in[8];
  const float* gcn1_b   = (const float*)d_in[9];
  const float* mask1    = (const float*)d_in[10];
  const float* gcn2_w   = (const float*)d_in[11];
  const float* gcn2_b   = (const float*)d_in[12];
  const float* mask2    = (const float*)d_in[13];
  const float* beta2    = (const float*)d_in[14];
  const float* attn_w1  = (const float*)d_in[15];
  const float* attn_b1  = (const float*)d_in[16];
  const float* attn_w2  = (const float*)d_in[17];
  const float* attn_b2  = (const float*)d_in[18];
  const float* cls_w1   = (const float*)d_in[19];
  const float* cls_b1   = (const float*)d_in[20];
  const float* ln_gamma = (const float*)d_in[21];
  const float* ln_beta  = (const float*)d_in[22];
  const float* cls_w2   = (const float*)d_in[23];
  const float* cls_b2   = (const float*)d_in[24];

  char* ws = (char*)d_ws;
  float* wsf = (float*)d_ws;
  unsigned short* w1t  = (unsigned short*)(ws + OFF_W1T);
  unsigned short* cw1h = (unsigned short*)(ws + OFF_CW1H);
  unsigned short* cw1l = (unsigned short*)(ws + OFF_CW1L);
  float* xcur_g = (float*)(ws + OFF_XCUR);

  // 4096B slack after pots for k_att's discarded row-15 reads
  long long avail = (long long)ws_size - (long long)OFF_DYN - 4096;
  long long per = PER_BATCH_POTS_B + PER_BATCH_CTX_B;
  int chunk = 4096;
  if (avail < per * 4096LL) {
    long long c = (avail > 0) ? (avail / per) : 64;
    if (c > 4096) c = 4096;
    c &= ~63LL;
    if (c < 64) c = 64;
    chunk = (int)c;
  }
  unsigned short* pots = (unsigned short*)(ws + OFF_DYN);
  unsigned short* ctxh = (unsigned short*)(ws + OFF_DYN + (size_t)chunk * PER_BATCH_POTS_B + 4096);
  unsigned short* ctxl = ctxh + (size_t)chunk * 2048;

  hipLaunchKernelGGL(k_prep, dim3(64), dim3(256), 0, stream,
                     mask1, mask2, conv_w, conv_b, bn_gamma, bn_beta, bn_mean, bn_var,
                     attn_w1, cls_w1, wsf, w1t, cw1h, cw1l);
  hipLaunchKernelGGL(k_conv, dim3(4096), dim3(256), 0, stream,
                     X_seq, wsf, xcur_g);

  for (int b0 = 0; b0 < 4096; b0 += chunk) {
    int cur = 4096 - b0;
    if (cur > chunk) cur = chunk;
    hipLaunchKernelGGL(k_main, dim3(cur), dim3(256), 0, stream,
                       L_norm, xcur_g, gcn1_w, gcn1_b, gcn2_w, gcn2_b, beta2,
                       wsf, pots, b0);
    hipLaunchKernelGGL(k_att, dim3(cur), dim3(256), 0, stream,
                       pots, w1t, attn_b1, attn_w2, attn_b2, ctxh, ctxl);
    hipLaunchKernelGGL(k_cls, dim3(cur / 16), dim3(256), 0, stream,
                       ctxh, ctxl, cw1h, cw1l, cls_b1, ln_gamma, ln_beta, cls_w2, cls_b2,
                       (float*)d_out, b0);
  }
}